// Round 17
// baseline (45.904 us; speedup 1.0000x reference)
//
#include <hip/hip_runtime.h>
#include <hip/hip_fp16.h>
#include <stdint.h>

typedef unsigned int u32;
typedef unsigned long long u64;
typedef unsigned short u16;

#define FACTOR  6.26f
#define D       2048
#define TPB     256
#define WPB     4        // one row per wave
#define CAP     128      // per-side candidate capacity (mean 82, sd 8.9 at TH=1.75)
#define TH      1.75f
#define TH_BITS 0x3FE00000u   // bits(1.75f)

// Seed ladder (float bits) around the 32nd-largest of 2048 N(0,1): 2.15 +/- 0.07.
#define SEED_MID  0x4009999Au   // 2.15f
#define SEED_LOW  0x40028F5Cu   // 2.04f
#define SEED_HIGH 0x401147AEu   // 2.27f

// ---- DPP wave64 primitives (VALU pipe) ----
template<int CTRL, int RM>
__device__ __forceinline__ u32 dpp_u32(u32 x) {
    return (u32)__builtin_amdgcn_update_dpp(0, (int)x, CTRL, RM, 0xF, true);
}
template<int CTRL, int RM>
__device__ __forceinline__ float dpp_f(float x) {
    return __int_as_float(
        __builtin_amdgcn_update_dpp(0, __float_as_int(x), CTRL, RM, 0xF, true));
}
__device__ __forceinline__ u32 dpp_scan_u32(u32 x) {
    x += dpp_u32<0x111, 0xF>(x);
    x += dpp_u32<0x112, 0xF>(x);
    x += dpp_u32<0x114, 0xF>(x);
    x += dpp_u32<0x118, 0xF>(x);
    x += dpp_u32<0x142, 0xA>(x);
    x += dpp_u32<0x143, 0xC>(x);
    return x;
}
__device__ __forceinline__ float dpp_sum_f(float v) {
    v += dpp_f<0x111, 0xF>(v);
    v += dpp_f<0x112, 0xF>(v);
    v += dpp_f<0x114, 0xF>(v);
    v += dpp_f<0x118, 0xF>(v);
    v += dpp_f<0x142, 0xA>(v);
    v += dpp_f<0x143, 0xC>(v);
    return __int_as_float(__builtin_amdgcn_readlane(__float_as_int(v), 63));
}

// shuffle reductions for the cold slow path only
__device__ __forceinline__ float wsum_f(float v) {
#pragma unroll
    for (int d = 1; d < 64; d <<= 1) v += __shfl_xor(v, d, 64);
    return v;
}
__device__ __forceinline__ u32 wsum_u(u32 v) {
#pragma unroll
    for (int d = 1; d < 64; d <<= 1) v += __shfl_xor(v, d, 64);
    return v;
}

__device__ __forceinline__ int cnt2f(u32 a, u32 b, u32 m) {
    return __popcll(__ballot(a >= m)) + __popcll(__ballot(b >= m));
}

struct Cut32 { u32 bF; u32 idxCut; };
// winner(elem) <=> bits(val) > bF || (bits(val) == bF && (2047-idx) >= idxCut)

__device__ __forceinline__ Cut32 find_cut32(u32 kf0, u32 kf1,
                                            u64 k0, u64 k1, int tot) {
    u32 bLo = TH_BITS;     int cLo = tot;
    u32 bHi = 0x7F800001u; int cHi = 0;
    {
        int c = cnt2f(kf0, kf1, SEED_MID);
        if (c == 32) { Cut32 r; r.bF = SEED_MID; r.idxCut = 0u; return r; }
        if (c > 32) {
            bLo = SEED_MID; cLo = c;
            int c2 = cnt2f(kf0, kf1, SEED_HIGH);
            if (c2 == 32) { Cut32 r; r.bF = SEED_HIGH; r.idxCut = 0u; return r; }
            if (c2 > 32) { bLo = SEED_HIGH; cLo = c2; } else { bHi = SEED_HIGH; cHi = c2; }
        } else {
            bHi = SEED_MID; cHi = c;
            int c2 = cnt2f(kf0, kf1, SEED_LOW);
            if (c2 == 32) { Cut32 r; r.bF = SEED_LOW; r.idxCut = 0u; return r; }
            if (c2 > 32) { bLo = SEED_LOW; cLo = c2; } else { bHi = SEED_LOW; cHi = c2; }
        }
    }
    int it = 0;
    while (bHi - bLo > 1u) {
        u32 bmid;
        if ((it & 1) || cHi == 0) {
            bmid = bLo + ((bHi - bLo) >> 1);
        } else {
            float fLo = __uint_as_float(bLo), fHi = __uint_as_float(bHi);
            float tt = (float)(cLo - 32) / (float)(cLo - cHi);
            u32 bs = __float_as_uint(fLo + tt * (fHi - fLo));
            bmid = (bs <= bLo) ? (bLo + 1u) : ((bs >= bHi) ? (bHi - 1u) : bs);
        }
        int c = cnt2f(kf0, kf1, bmid);
        if (c == 32) { Cut32 r; r.bF = bmid; r.idxCut = 0u; return r; }
        if (c > 32) { bLo = bmid; cLo = c; } else { bHi = bmid; cHi = c; }
        ++it;
    }
    int fill = 32 - cHi;
    u32 il0 = (u32)(k0 & 0x7FFull), il1 = (u32)(k1 & 0x7FFull);
    u32 lo = 0u, hi = 2048u;
    while (hi - lo > 1u) {
        u32 m = (lo + hi) >> 1;
        int c = __popcll(__ballot(kf0 == bLo && il0 >= m))
              + __popcll(__ballot(kf1 == bLo && il1 >= m));
        if (c >= fill) { lo = m; if (c == fill) break; } else hi = m;
    }
    Cut32 r; r.bF = bLo; r.idxCut = lo;
    return r;
}

// Cold exact fallback (degenerate rows only), atomicAdd on top of staged row.
__device__ __attribute__((noinline))
void slow_side(const float4* __restrict__ xr, float* __restrict__ outrow,
               int lane, int neg, float sum) {
    u64 lo = 0ull, hi = ((u64)0x7F800001u) << 32;
    while (hi - lo > 1ull) {
        u64 mid = lo + ((hi - lo) >> 1);
        u32 cl = 0;
#pragma unroll 1
        for (int q = 0; q < 8; ++q) {
            float4 f = xr[q * 64 + lane];
            float vv[4] = {f.x, f.y, f.z, f.w};
#pragma unroll
            for (int c = 0; c < 4; ++c) {
                float v = neg ? -vv[c] : vv[c];
                float pv = v > 0.f ? v : 0.f;
                int idx = q * 256 + lane * 4 + c;
                u64 k = ((u64)__float_as_uint(pv) << 32) | (u64)(u32)(2047 - idx);
                cl += (k >= mid) ? 1u : 0u;
            }
        }
        u32 c = wsum_u(cl);
        if (c >= 32u) { lo = mid; if (c == 32u) break; } else hi = mid;
    }
    float ts = 0.f;
#pragma unroll 1
    for (int q = 0; q < 8; ++q) {
        float4 f = xr[q * 64 + lane];
        float vv[4] = {f.x, f.y, f.z, f.w};
#pragma unroll
        for (int c = 0; c < 4; ++c) {
            float v = neg ? -vv[c] : vv[c];
            float pv = v > 0.f ? v : 0.f;
            int idx = q * 256 + lane * 4 + c;
            u64 k = ((u64)__float_as_uint(pv) << 32) | (u64)(u32)(2047 - idx);
            if (k >= lo) ts += pv;
        }
    }
    ts = wsum_f(ts);
    float tmp = FACTOR * (sum - ts);
    float sgn = neg ? -1.f : 1.f;
#pragma unroll 1
    for (int q = 0; q < 8; ++q) {
        float4 f = xr[q * 64 + lane];
        float vv[4] = {f.x, f.y, f.z, f.w};
#pragma unroll
        for (int c = 0; c < 4; ++c) {
            float v = neg ? -vv[c] : vv[c];
            float pv = v > 0.f ? v : 0.f;
            int idx = q * 256 + lane * 4 + c;
            u64 k = ((u64)__float_as_uint(pv) << 32) | (u64)(u32)(2047 - idx);
            if (k >= lo) atomicAdd(&outrow[idx], sgn * (pv + tmp));
        }
    }
}

__global__ void __launch_bounds__(TPB, 8)
kcomp_kernel(const float* __restrict__ x, float* __restrict__ out) {
    // 4 KiB per wave, phase-overlaid: [lists: 2 x CAP x u64 = 2 KiB] then
    // [staged fp16 row: 2048 x u16 = 4 KiB]. Lists die (into regs) before
    // the row is zeroed over them. 16 KiB/block total.
    // Ordering within a wave relies on the in-order DS pipe; sched_barrier(0)
    // pins the compiler's instruction order at the overlay boundaries.
    __shared__ __align__(16) u16 s_mem[WPB][D];

    const int t    = threadIdx.x;
    const int lane = t & 63;
    const int wave = t >> 6;
    const size_t rbase = (size_t)(blockIdx.x * WPB + wave) * D;

    const float4* xr     = reinterpret_cast<const float4*>(x + rbase);
    float4*       out4   = reinterpret_cast<float4*>(out + rbase);
    float*        outrow = out + rbase;

    u64* listP = reinterpret_cast<u64*>(&s_mem[wave][0]);
    u64* listN = listP + CAP;
    u16* svrow = s_mem[wave];
    uint4* sv4 = reinterpret_cast<uint4*>(svrow);

    // ---- pass 1: load row; plain sum + abs-sum
    float rv[32];
    float s = 0.f, sa = 0.f;
    u32 cP = 0, cN = 0;
#pragma unroll
    for (int q = 0; q < 8; ++q) {
        float4 f = xr[q * 64 + lane];
        rv[q*4+0] = f.x; rv[q*4+1] = f.y; rv[q*4+2] = f.z; rv[q*4+3] = f.w;
#pragma unroll
        for (int c = 0; c < 4; ++c) {
            float v = rv[q*4+c];
            s  += v;
            sa += __builtin_fabsf(v);
            cP += v > TH  ? 1u : 0u;
            cN += v < -TH ? 1u : 0u;
        }
    }

    // ---- packed prefix scan (DPP) for compaction offsets
    u32 packed = cP | (cN << 16);
    u32 inc = dpp_scan_u32(packed);
    u32 tot = (u32)__builtin_amdgcn_readlane((int)inc, 63);
    u32 exc = inc - packed;
    u32 totP = tot & 0xffffu, totN = tot >> 16;
    u32 offP = exc & 0xffffu, offN = exc >> 16;
    float sw  = dpp_sum_f(s);
    float saw = dpp_sum_f(sa);
    float sumP = 0.5f * (saw + sw);
    float sumN = 0.5f * (saw - sw);

    const bool fastP = (totP >= 32u && totP <= CAP);
    const bool fastN = (totN >= 32u && totN <= CAP);

    // ---- pass 2: compact u64 keys to LDS lists; rv dies here
#pragma unroll
    for (int q = 0; q < 8; ++q) {
#pragma unroll
        for (int c = 0; c < 4; ++c) {
            float v = rv[q*4+c];
            u32 fi = (u32)(q * 256 + lane * 4 + c);
            if (fastP && v > TH)
                listP[offP++] = ((u64)__float_as_uint(v)  << 32) | (u64)(2047u - fi);
            if (fastN && v < -TH)
                listN[offN++] = ((u64)__float_as_uint(-v) << 32) | (u64)(2047u - fi);
        }
    }

    // ---- load lists to regs (2 slots/lane); lists die into registers here
    u64 p0 = 0, p1 = 0, n0 = 0, n1 = 0;
    if (fastP) {
        p0 = (lane      < (int)totP) ? listP[lane]      : 0ull;
        p1 = (lane + 64 < (int)totP) ? listP[lane + 64] : 0ull;
    }
    if (fastN) {
        n0 = (lane      < (int)totN) ? listN[lane]      : 0ull;
        n1 = (lane + 64 < (int)totN) ? listN[lane + 64] : 0ull;
    }
    // Compiler fence only: DS pipe serves same-wave ops in order, so the list
    // reads complete before the overlay zeros below reach the same bytes.
    __builtin_amdgcn_sched_barrier(0);

    // ---- zero the staged fp16 row over the dead lists (overlaps find_cut)
#pragma unroll
    for (int q = 0; q < 4; ++q)
        sv4[q * 64 + lane] = make_uint4(0u, 0u, 0u, 0u);

    u32 pf0 = (u32)(p0 >> 32), pf1 = (u32)(p1 >> 32);
    u32 nf0 = (u32)(n0 >> 32), nf1 = (u32)(n1 >> 32);

    // ---- selection + energy terms (ballot/VALU only; DS zeros drain behind)
    Cut32 cutP; cutP.bF = 0u; cutP.idxCut = 0u;
    Cut32 cutN; cutN.bF = 0u; cutN.idxCut = 0u;
    float PtmpP = 0.f, NtmpN = 0.f;
    if (fastP) {
        cutP = find_cut32(pf0, pf1, p0, p1, (int)totP);
        float ts = 0.f;
        if (pf0 > cutP.bF || (pf0 == cutP.bF && (u32)(p0 & 0x7FFull) >= cutP.idxCut)) ts += __uint_as_float(pf0);
        if (pf1 > cutP.bF || (pf1 == cutP.bF && (u32)(p1 & 0x7FFull) >= cutP.idxCut)) ts += __uint_as_float(pf1);
        ts = dpp_sum_f(ts);
        PtmpP = FACTOR * (sumP - ts);
    }
    if (fastN) {
        cutN = find_cut32(nf0, nf1, n0, n1, (int)totN);
        float ts = 0.f;
        if (nf0 > cutN.bF || (nf0 == cutN.bF && (u32)(n0 & 0x7FFull) >= cutN.idxCut)) ts += __uint_as_float(nf0);
        if (nf1 > cutN.bF || (nf1 == cutN.bF && (u32)(n1 & 0x7FFull) >= cutN.idxCut)) ts += __uint_as_float(nf1);
        ts = dpp_sum_f(ts);
        NtmpN = FACTOR * (sumN - ts);
    }

    // ---- scatter winners into the staged fp16 row (|v|>1.75 so fp16 bits
    // 0x0000 is a safe "empty" sentinel; converts to 0.0f for free).
    __builtin_amdgcn_sched_barrier(0);
    if (fastP) {
#pragma unroll
        for (int sl = 0; sl < 2; ++sl) {
            u64 k  = (sl == 0) ? p0  : p1;
            u32 kf = (sl == 0) ? pf0 : pf1;
            u32 il = (u32)(k & 0x7FFull);
            if (kf > cutP.bF || (kf == cutP.bF && il >= cutP.idxCut))
                svrow[2047 - (int)il] =
                    __half_as_ushort(__float2half_rn(__uint_as_float(kf) + PtmpP));
        }
    }
    if (fastN) {
#pragma unroll
        for (int sl = 0; sl < 2; ++sl) {
            u64 k  = (sl == 0) ? n0  : n1;
            u32 kf = (sl == 0) ? nf0 : nf1;
            u32 il = (u32)(k & 0x7FFull);
            if (kf > cutN.bF || (kf == cutN.bF && il >= cutN.idxCut))
                svrow[2047 - (int)il] =
                    __half_as_ushort(__float2half_rn(-(__uint_as_float(kf) + NtmpN)));
        }
    }
    __builtin_amdgcn_sched_barrier(0);

    // ---- readback (b128) + decode + single full-line global store.
    // 0x0000 converts to 0.0f, so no empty-slot select is needed.
#pragma unroll
    for (int qq = 0; qq < 4; ++qq) {
        uint4 w = sv4[qq * 64 + lane];          // 8 fp16
        u32 ws[4] = {w.x, w.y, w.z, w.w};
        float o[8];
#pragma unroll
        for (int c = 0; c < 4; ++c) {
            __half_raw hlo; hlo.x = (u16)(ws[c] & 0xFFFFu);
            __half_raw hhi; hhi.x = (u16)(ws[c] >> 16);
            o[2*c]   = __half2float(__half(hlo));
            o[2*c+1] = __half2float(__half(hhi));
        }
        int ob = qq * 128 + lane * 2;
        out4[ob]     = make_float4(o[0], o[1], o[2], o[3]);
        out4[ob + 1] = make_float4(o[4], o[5], o[6], o[7]);
    }

    // ---- degenerate-row fallback: drain our stores, then exact atomics.
    const bool anyslow = !(fastP && fastN);
    if (anyslow) {
        asm volatile("s_waitcnt vmcnt(0) lgkmcnt(0)" ::: "memory");
        if (!fastP) slow_side(xr, outrow, lane, 0, sumP);
        if (!fastN) slow_side(xr, outrow, lane, 1, sumN);
    }
}

extern "C" void kernel_launch(void* const* d_in, const int* in_sizes, int n_in,
                              void* d_out, int out_size, void* d_ws, size_t ws_size,
                              hipStream_t stream) {
    const float* x = (const float*)d_in[0];
    float* out = (float*)d_out;
    const int rows = in_sizes[0] / D;          // 16384
    kcomp_kernel<<<rows / WPB, TPB, 0, stream>>>(x, out);
}